// Round 1
// baseline (1297.305 us; speedup 1.0000x reference)
//
#include <hip/hip_runtime.h>
#include <math.h>

// LocalizationLoss: B rows of [4 box preds | 1000 logits] (fp32).
// loss = mean_rows( 0.25*sum((box_pred - box_true)^2) + (logsumexp(logits) - logits[cls]) )
// One wave per row; coalesced float4 logit loads; shuffle-butterfly logsumexp.

#define ROWLEN 1004
#define NVEC   250   // 1000 logits / 4

__global__ __launch_bounds__(256) void loc_loss_kernel(
    const float* __restrict__ output,
    const float* __restrict__ target,
    float* __restrict__ out,
    int n_rows, float inv_n)
{
    const int lane          = threadIdx.x & 63;
    const int wave_in_block = threadIdx.x >> 6;
    const int wave_id       = blockIdx.x * 4 + wave_in_block;
    const int num_waves     = gridDim.x * 4;

    float acc = 0.0f;

    for (int row = wave_id; row < n_rows; row += num_waves) {
        const float* rb = output + (size_t)row * ROWLEN;

        // lane 0: target scalars, box preds, and the class-logit gather
        float t0 = 0.f, t1 = 0.f, t2 = 0.f, t3 = 0.f;
        float bp0 = 0.f, bp1 = 0.f, bp2 = 0.f, bp3 = 0.f;
        float logit_c = 0.f;
        if (lane == 0) {
            const float* tr = target + (size_t)row * 5;
            t0 = tr[0]; t1 = tr[1]; t2 = tr[2]; t3 = tr[3];
            int cls = (int)tr[4];
            logit_c = rb[4 + cls];
            bp0 = rb[0]; bp1 = rb[1]; bp2 = rb[2]; bp3 = rb[3];
        }

        // coalesced float4 loads of the 1000 logits (250 vecs)
        const float4* lb = (const float4*)(rb + 4);
        float4 v0 = lb[lane];
        float4 v1 = lb[lane + 64];
        float4 v2 = lb[lane + 128];
        float4 v3;
        if (lane < NVEC - 192) {
            v3 = lb[lane + 192];
        } else {
            v3.x = -INFINITY; v3.y = -INFINITY; v3.z = -INFINITY; v3.w = -INFINITY;
        }

        // lane-local max of up to 16 values
        float m = fmaxf(fmaxf(fmaxf(v0.x, v0.y), fmaxf(v0.z, v0.w)),
                        fmaxf(fmaxf(v1.x, v1.y), fmaxf(v1.z, v1.w)));
        m = fmaxf(m, fmaxf(fmaxf(v2.x, v2.y), fmaxf(v2.z, v2.w)));
        m = fmaxf(m, fmaxf(fmaxf(v3.x, v3.y), fmaxf(v3.z, v3.w)));

        // lane-local sum of exp(x - m); exp(-inf - m) == 0 handles the tail
        float s = __expf(v0.x - m) + __expf(v0.y - m) + __expf(v0.z - m) + __expf(v0.w - m);
        s += __expf(v1.x - m) + __expf(v1.y - m) + __expf(v1.z - m) + __expf(v1.w - m);
        s += __expf(v2.x - m) + __expf(v2.y - m) + __expf(v2.z - m) + __expf(v2.w - m);
        s += __expf(v3.x - m) + __expf(v3.y - m) + __expf(v3.z - m) + __expf(v3.w - m);

        // wave butterfly reduction of (m, s)
        #pragma unroll
        for (int off = 1; off < 64; off <<= 1) {
            float mo = __shfl_xor(m, off, 64);
            float so = __shfl_xor(s, off, 64);
            float M  = fmaxf(m, mo);
            s = s * __expf(m - M) + so * __expf(mo - M);
            m = M;
        }

        if (lane == 0) {
            float lse = m + __logf(s);
            float cx = (t0 + t2) * 0.5f;
            float cy = (t1 + t3) * 0.5f;
            float w  = t2 - t0;
            float h  = t3 - t1;
            float dx = bp0 - cx, dy = bp1 - cy, dw = bp2 - w, dh = bp3 - h;
            float loc = (dx * dx + dy * dy + dw * dw + dh * dh) * 0.25f;
            acc += loc + (lse - logit_c);
        }
    }

    __shared__ float part[4];
    if (lane == 0) part[wave_in_block] = acc;
    __syncthreads();
    if (threadIdx.x == 0) {
        float tot = (part[0] + part[1] + part[2] + part[3]) * inv_n;
        atomicAdd(out, tot);
    }
}

extern "C" void kernel_launch(void* const* d_in, const int* in_sizes, int n_in,
                              void* d_out, int out_size, void* d_ws, size_t ws_size,
                              hipStream_t stream) {
    const float* output = (const float*)d_in[0];
    const float* target = (const float*)d_in[1];
    float* out = (float*)d_out;

    int n_rows = in_sizes[0] / ROWLEN;
    float inv_n = 1.0f / (float)n_rows;

    // d_out is poisoned to 0xAA before every launch — zero it for the atomics
    hipMemsetAsync(out, 0, out_size * sizeof(float), stream);

    loc_loss_kernel<<<4096, 256, 0, stream>>>(output, target, out, n_rows, inv_n);
}